// Round 4
// baseline (253.922 us; speedup 1.0000x reference)
//
#include <hip/hip_runtime.h>
#include <stdint.h>

#define Bn  4
#define Sn  4096
#define DIN 512
#define Dn  64
#define RS  0.18033688011112042f   /* (1/8) * log2(e) */
#define MASKV (-3.0e38f)

typedef __bf16 bf16;
typedef __bf16 bf16x8 __attribute__((ext_vector_type(8)));
typedef float  f32x16 __attribute__((ext_vector_type(16)));
typedef unsigned short ushort8_t __attribute__((ext_vector_type(8)));

__device__ __forceinline__ f32x16 mfma32(bf16x8 a, bf16x8 b, f32x16 c) {
  return __builtin_amdgcn_mfma_f32_32x32x16_bf16(a, b, c, 0, 0, 0);
}

__device__ __forceinline__ f32x16 fzero16() {
  f32x16 v;
#pragma unroll
  for (int i = 0; i < 16; ++i) v[i] = 0.f;
  return v;
}

// 16B fragment read (8 bf16) from a row-major [*][64] bf16 LDS tile with
// byte ^= ((row&7)<<4) XOR swizzle (T2; bank-conflict-free ds_read_b128).
__device__ __forceinline__ bf16x8 frag_ld(const unsigned short* base, int row, int k) {
  int off = (row << 7) + (k << 1);
  off ^= (row & 7) << 4;
  return *(const bf16x8*)((const char*)base + off);
}

// async global->LDS, 16B per lane; LDS dest must be wave-uniform base.
__device__ __forceinline__ void async16(void* lds, const void* g) {
  __builtin_amdgcn_global_load_lds(
      (const __attribute__((address_space(1))) unsigned int*)g,
      (__attribute__((address_space(3))) unsigned int*)lds, 16, 0, 0);
}

__device__ __forceinline__ unsigned int pk2(float a, float b) {
  unsigned short ra = __builtin_bit_cast(unsigned short, (bf16)a);
  unsigned short rb = __builtin_bit_cast(unsigned short, (bf16)b);
  return (unsigned int)ra | ((unsigned int)rb << 16);
}

// ---------------------------------------------------------------------------
// Projection: Y[16384x64] = X[16384x512] @ W[64x512]^T, fp32 in, hi/lo bf16 out.
// One launch handles Q, K, V (mat = blockIdx.x >> 8). 64-row tile per block.
// ---------------------------------------------------------------------------
__global__ __launch_bounds__(256) void proj_kernel(
    const float* __restrict__ Xq, const float* __restrict__ Xk, const float* __restrict__ Xv,
    const float* __restrict__ Wq, const float* __restrict__ Wk, const float* __restrict__ Wv,
    unsigned short* __restrict__ Qh, unsigned short* __restrict__ Ql,
    unsigned short* __restrict__ Kh, unsigned short* __restrict__ Kl,
    unsigned short* __restrict__ Vh, unsigned short* __restrict__ Vl)
{
  int mat = blockIdx.x >> 8;
  int rt  = blockIdx.x & 255;
  const float* X = (mat == 0) ? Xq : (mat == 1) ? Xk : Xv;
  const float* W = (mat == 0) ? Wq : (mat == 1) ? Wk : Wv;
  unsigned short* Yh = (mat == 0) ? Qh : (mat == 1) ? Kh : Vh;
  unsigned short* Yl = (mat == 0) ? Ql : (mat == 1) ? Kl : Vl;

  __shared__ unsigned short Xh_s[64 * 64];
  __shared__ unsigned short Xl_s[64 * 64];
  __shared__ unsigned short Wh_s[64 * 64];
  __shared__ unsigned short Wl_s[64 * 64];

  int tid  = threadIdx.x;
  int lane = tid & 63;
  int wv   = tid >> 6;
  int h    = lane >> 5;
  int c    = lane & 31;
  int srow = tid >> 2;   // staging row 0..63
  int sq   = tid & 3;

  int row0 = rt * 64;

  f32x16 acc = fzero16();

  for (int k0 = 0; k0 < DIN; k0 += 64) {
#pragma unroll
    for (int j = 0; j < 4; ++j) {
      int kk = j * 16 + sq * 4;
      int off = ((srow << 7) + (kk << 1)) ^ ((srow & 7) << 4);

      float4 xv = *(const float4*)(X + (size_t)(row0 + srow) * DIN + k0 + kk);
      bf16 bx0 = (bf16)xv.x, bx1 = (bf16)xv.y, bx2 = (bf16)xv.z, bx3 = (bf16)xv.w;
      uint2 hw, lw;
      hw.x = (unsigned)__builtin_bit_cast(unsigned short, bx0) |
             ((unsigned)__builtin_bit_cast(unsigned short, bx1) << 16);
      hw.y = (unsigned)__builtin_bit_cast(unsigned short, bx2) |
             ((unsigned)__builtin_bit_cast(unsigned short, bx3) << 16);
      lw.x = pk2(xv.x - (float)bx0, xv.y - (float)bx1);
      lw.y = pk2(xv.z - (float)bx2, xv.w - (float)bx3);
      *(uint2*)((char*)Xh_s + off) = hw;
      *(uint2*)((char*)Xl_s + off) = lw;

      float4 wv4 = *(const float4*)(W + (size_t)srow * DIN + k0 + kk);
      bf16 bw0 = (bf16)wv4.x, bw1 = (bf16)wv4.y, bw2 = (bf16)wv4.z, bw3 = (bf16)wv4.w;
      uint2 hw2, lw2;
      hw2.x = (unsigned)__builtin_bit_cast(unsigned short, bw0) |
              ((unsigned)__builtin_bit_cast(unsigned short, bw1) << 16);
      hw2.y = (unsigned)__builtin_bit_cast(unsigned short, bw2) |
              ((unsigned)__builtin_bit_cast(unsigned short, bw3) << 16);
      lw2.x = pk2(wv4.x - (float)bw0, wv4.y - (float)bw1);
      lw2.y = pk2(wv4.z - (float)bw2, wv4.w - (float)bw3);
      *(uint2*)((char*)Wh_s + off) = hw2;
      *(uint2*)((char*)Wl_s + off) = lw2;
    }
    __syncthreads();

    int ar   = (wv >> 1) * 32 + c;  // A-frag row (X row, m = lane&31)
    int bcol = (wv & 1) * 32 + c;   // B-frag col (W row = output col, n = lane&31)
#pragma unroll
    for (int kk = 0; kk < 4; ++kk) {
      int kp = kk * 16 + h * 8;
      bf16x8 ah = frag_ld(Xh_s, ar, kp);
      bf16x8 al = frag_ld(Xl_s, ar, kp);
      bf16x8 bh = frag_ld(Wh_s, bcol, kp);
      bf16x8 bl = frag_ld(Wl_s, bcol, kp);
      acc = mfma32(ah, bh, acc);
      acc = mfma32(ah, bl, acc);
      acc = mfma32(al, bh, acc);
    }
    __syncthreads();
  }

  // C/D: row = (r&3) + 8*(r>>2) + 4*(lane>>5), col = lane&31  [guide m74/m101]
  int wr = (wv >> 1) * 32;
  int wc = (wv & 1) * 32;
#pragma unroll
  for (int r = 0; r < 16; ++r) {
    int rowl = (r & 3) + ((r >> 2) << 3) + h * 4;
    size_t o = (size_t)(row0 + wr + rowl) * Dn + wc + c;
    float v = acc[r];
    bf16 hv = (bf16)v;
    Yh[o] = __builtin_bit_cast(unsigned short, hv);
    Yl[o] = __builtin_bit_cast(unsigned short, (bf16)(v - (float)hv));
  }
}

// ---------------------------------------------------------------------------
// Transpose V (hi/lo): [B][S][64] -> [B][64][S]
// ---------------------------------------------------------------------------
__global__ __launch_bounds__(256) void transpose_kernel(
    const unsigned short* __restrict__ Vh, const unsigned short* __restrict__ Vl,
    unsigned short* __restrict__ Vth, unsigned short* __restrict__ Vtl)
{
  int bx = blockIdx.x;
  int b  = bx >> 6;
  int s0 = (bx & 63) * 64;
  __shared__ unsigned short th[64][72];
  __shared__ unsigned short tl[64][72];
  int t = threadIdx.x;
  int r = t >> 2, q4 = t & 3;

  const unsigned short* srch = Vh + ((size_t)(b * Sn + s0 + r)) * Dn + q4 * 16;
  const unsigned short* srcl = Vl + ((size_t)(b * Sn + s0 + r)) * Dn + q4 * 16;
  ushort8_t a0 = *(const ushort8_t*)srch;
  ushort8_t a1 = *(const ushort8_t*)(srch + 8);
  ushort8_t b0 = *(const ushort8_t*)srcl;
  ushort8_t b1 = *(const ushort8_t*)(srcl + 8);
  *(ushort8_t*)&th[r][q4 * 16]     = a0;
  *(ushort8_t*)&th[r][q4 * 16 + 8] = a1;
  *(ushort8_t*)&tl[r][q4 * 16]     = b0;
  *(ushort8_t*)&tl[r][q4 * 16 + 8] = b1;
  __syncthreads();

  int d = t >> 2, sp = t & 3;
  ushort8_t o0, o1, p0, p1;
#pragma unroll
  for (int i = 0; i < 8; ++i) {
    o0[i] = th[sp * 16 + i][d];
    o1[i] = th[sp * 16 + 8 + i][d];
    p0[i] = tl[sp * 16 + i][d];
    p1[i] = tl[sp * 16 + 8 + i][d];
  }
  unsigned short* dsth = Vth + ((size_t)(b * Dn + d)) * Sn + s0 + sp * 16;
  unsigned short* dstl = Vtl + ((size_t)(b * Dn + d)) * Sn + s0 + sp * 16;
  *(ushort8_t*)dsth       = o0;
  *(ushort8_t*)(dsth + 8) = o1;
  *(ushort8_t*)dstl       = p0;
  *(ushort8_t*)(dstl + 8) = p1;
}

// ---------------------------------------------------------------------------
// Flash attention, split-K (even/odd key tiles), swapped-QK^T 32x32x16 MFMA,
// hi/lo split precision. 512 blocks x 128 threads (2 waves of 32 q-rows).
// Writes per-(half,row) partials: O[64], m, l  (stride 68 floats).
// ---------------------------------------------------------------------------
__global__ __launch_bounds__(128) void attn_kernel(
    const unsigned short* __restrict__ Qh, const unsigned short* __restrict__ Ql,
    const unsigned short* __restrict__ Kh, const unsigned short* __restrict__ Kl,
    const unsigned short* __restrict__ Vth, const unsigned short* __restrict__ Vtl,
    float* __restrict__ part)
{
  int bx   = blockIdx.x;
  int qt   = 63 - (bx >> 3);     // largest q-tiles dispatched first
  int half = (bx >> 2) & 1;
  int b    = bx & 3;
  int tid  = threadIdx.x;
  int wv   = tid >> 6;
  int lane = tid & 63;
  int h    = lane >> 5;
  int c    = lane & 31;
  int q_base = qt * 64 + wv * 32;

  __shared__ unsigned short Kh_s[2][64 * 64];
  __shared__ unsigned short Kl_s[2][64 * 64];
  __shared__ unsigned short Vh_s[2][64 * 64];
  __shared__ unsigned short Vl_s[2][64 * 64];

  // Q B-fragments (B[k=d][n=q] = Q[q][d]); row-major 16B chunks from global.
  bf16x8 qhi[4], qlo[4];
  {
    const unsigned short* qp  = Qh + ((size_t)(b * Sn) + q_base + c) * Dn;
    const unsigned short* qp2 = Ql + ((size_t)(b * Sn) + q_base + c) * Dn;
#pragma unroll
    for (int kk = 0; kk < 4; ++kk) {
      qhi[kk] = *(const bf16x8*)(qp + kk * 16 + h * 8);
      qlo[kk] = *(const bf16x8*)(qp2 + kk * 16 + h * 8);
    }
  }

  f32x16 o0 = fzero16(), o1 = fzero16();
  float m = MASKV, lsum = 0.f;
  int nt = qt + 1;

  int l8   = lane >> 3;
  int slot = (lane & 7) ^ (l8 & 7);   // pre-swizzled global 16B-slot (rule #21)

  auto stage = [&](int sb, int ti) {
    size_t j0 = (size_t)ti * 64;
#pragma unroll
    for (int i = 0; i < 4; ++i) {
      int rowbase = (wv * 4 + i) * 8;
      int row = rowbase + l8;
      const char* gk  = (const char*)Kh + ((size_t)(b * Sn) + j0 + row) * 128 + slot * 16;
      const char* gk2 = (const char*)Kl + ((size_t)(b * Sn) + j0 + row) * 128 + slot * 16;
      async16(&Kh_s[sb][rowbase * 64], gk);
      async16(&Kl_s[sb][rowbase * 64], gk2);
      const char* gv  = (const char*)Vth + ((size_t)(b * Dn) + row) * (Sn * 2) + j0 * 2 + slot * 16;
      const char* gv2 = (const char*)Vtl + ((size_t)(b * Dn) + row) * (Sn * 2) + j0 * 2 + slot * 16;
      async16(&Vh_s[sb][rowbase * 64], gv);
      async16(&Vl_s[sb][rowbase * 64], gv2);
    }
  };

  int buf = 0;
  stage(0, half);
  __syncthreads();

  for (int ti = half; ti < nt; ti += 2) {
    if (ti + 2 < nt) stage(buf ^ 1, ti + 2);

    const unsigned short* KhT = Kh_s[buf];
    const unsigned short* KlT = Kl_s[buf];
    const unsigned short* VhT = Vh_s[buf];
    const unsigned short* VlT = Vl_s[buf];

    // --- QK^T (swapped: S^T[key][q]) ---
    f32x16 s0a = fzero16(), s0b = fzero16(), s1a = fzero16(), s1b = fzero16();
#pragma unroll
    for (int kk = 0; kk < 4; ++kk) {
      int kp = kk * 16 + h * 8;
      bf16x8 k0h = frag_ld(KhT, c, kp);
      bf16x8 k0l = frag_ld(KlT, c, kp);
      bf16x8 k1h = frag_ld(KhT, 32 + c, kp);
      bf16x8 k1l = frag_ld(KlT, 32 + c, kp);
      if (kk < 2) {
        s0a = mfma32(k0h, qhi[kk], s0a); s0a = mfma32(k0h, qlo[kk], s0a); s0a = mfma32(k0l, qhi[kk], s0a);
        s1a = mfma32(k1h, qhi[kk], s1a); s1a = mfma32(k1h, qlo[kk], s1a); s1a = mfma32(k1l, qhi[kk], s1a);
      } else {
        s0b = mfma32(k0h, qhi[kk], s0b); s0b = mfma32(k0h, qlo[kk], s0b); s0b = mfma32(k0l, qhi[kk], s0b);
        s1b = mfma32(k1h, qhi[kk], s1b); s1b = mfma32(k1h, qlo[kk], s1b); s1b = mfma32(k1l, qhi[kk], s1b);
      }
    }
    f32x16 s0 = s0a + s0b;
    f32x16 s1 = s1a + s1b;

    // --- causal mask (diagonal tile only): key >= q  -> MASKV ---
    if (ti == qt) {
      int qrel = wv * 32 + c;
#pragma unroll
      for (int r = 0; r < 16; ++r) {
        int koff = (r & 3) + ((r >> 2) << 3) + h * 4;
        if (koff >= qrel)      s0[r] = MASKV;
        if (32 + koff >= qrel) s1[r] = MASKV;
      }
    }

    // --- online softmax (lane holds 32 keys of q-row c; partner = lane^32) ---
    float mt = s0[0];
#pragma unroll
    for (int r = 1; r < 16; ++r) mt = fmaxf(mt, s0[r]);
#pragma unroll
    for (int r = 0; r < 16; ++r) mt = fmaxf(mt, s1[r]);
    mt = fmaxf(mt, __shfl_xor(mt, 32, 64));
    float mnew = fmaxf(m, mt);
    float al = exp2f((m - mnew) * RS);

    float p0[16], p1[16];
    float rsum = 0.f;
#pragma unroll
    for (int r = 0; r < 16; ++r) {
      p0[r] = exp2f((s0[r] - mnew) * RS);
      p1[r] = exp2f((s1[r] - mnew) * RS);
      rsum += p0[r] + p1[r];
    }
    rsum += __shfl_xor(rsum, 32, 64);
    lsum = lsum * al + rsum;
    m = mnew;

    // --- rescale O (acc rows are C/D rows; fetch alpha from the q-owner lane) ---
#pragma unroll
    for (int r = 0; r < 16; ++r) {
      int koff = (r & 3) + ((r >> 2) << 3) + h * 4;
      float ar = __shfl(al, (lane & 32) | koff, 64);
      o0[r] *= ar;
      o1[r] *= ar;
    }

    // --- PV: out[q][d] += P[q][keys] * V[keys][d] ---
#pragma unroll
    for (int ks = 0; ks < 2; ++ks) {
#pragma unroll
      for (int kk2 = 0; kk2 < 2; ++kk2) {
        float e0[4], e1[4];
#pragma unroll
        for (int x = 0; x < 4; ++x) {
          float vh0 = ks ? p1[(2 * kk2 + 0) * 4 + x] : p0[(2 * kk2 + 0) * 4 + x];
          float vh1 = ks ? p1[(2 * kk2 + 1) * 4 + x] : p0[(2 * kk2 + 1) * 4 + x];
          float own  = h ? vh1 : vh0;
          float send = h ? vh0 : vh1;
          float recv = __shfl_xor(send, 32, 64);
          e0[x] = h ? recv : own;   // frag elements e = 0..3
          e1[x] = h ? own : recv;   // frag elements e = 4..7
        }
        bf16x8 pah, pal;
#pragma unroll
        for (int x = 0; x < 4; ++x) {
          bf16 hh = (bf16)e0[x];
          pah[x] = hh;
          pal[x] = (bf16)(e0[x] - (float)hh);
          bf16 h2 = (bf16)e1[x];
          pah[4 + x] = h2;
          pal[4 + x] = (bf16)(e1[x] - (float)h2);
        }
        int kp = ks * 32 + kk2 * 16 + h * 8;
        bf16x8 v0h = frag_ld(VhT, c, kp);
        bf16x8 v0l = frag_ld(VlT, c, kp);
        bf16x8 v1h = frag_ld(VhT, 32 + c, kp);
        bf16x8 v1l = frag_ld(VlT, 32 + c, kp);
        o0 = mfma32(pah, v0h, o0);
        o0 = mfma32(pah, v0l, o0);
        o0 = mfma32(pal, v0h, o0);
        o1 = mfma32(pah, v1h, o1);
        o1 = mfma32(pah, v1l, o1);
        o1 = mfma32(pal, v1h, o1);
      }
    }

    __syncthreads();
    buf ^= 1;
  }

  // --- write partials: [half][b][s]: O[64], m, l (stride 68 f32) ---
  float* pb = part + ((size_t)(half * Bn + b) * Sn + q_base) * 68;
#pragma unroll
  for (int r = 0; r < 16; ++r) {
    int koff = (r & 3) + ((r >> 2) << 3) + h * 4;
    float* pr = pb + (size_t)koff * 68;
    pr[c]      = o0[r];
    pr[32 + c] = o1[r];
  }
  if (h == 0) {
    float* pr = pb + (size_t)c * 68;
    pr[64] = m;
    pr[65] = lsum;
  }
}

// ---------------------------------------------------------------------------
// Combine the two split-K partials; zero row 0 (mean-V kernel fills it).
// ---------------------------------------------------------------------------
__global__ __launch_bounds__(256) void combine_kernel(
    const float* __restrict__ part, float* __restrict__ out)
{
  size_t idx = (size_t)blockIdx.x * 256 + threadIdx.x;
  int d = (int)(idx & 63);
  int s = (int)((idx >> 6) & (Sn - 1));
  int b = (int)(idx >> 18);
  const float* p0 = part + ((size_t)(0 * Bn + b) * Sn + s) * 68;
  const float* p1 = part + ((size_t)(1 * Bn + b) * Sn + s) * 68;
  float m0 = p0[64], l0 = p0[65];
  float m1 = p1[64], l1 = p1[65];
  float ms = fmaxf(m0, m1);
  float a0 = exp2f((m0 - ms) * RS);
  float a1 = exp2f((m1 - ms) * RS);
  float num = a0 * p0[d] + a1 * p1[d];
  float den = a0 * l0 + a1 * l1;
  out[idx] = (s == 0) ? 0.0f : (num / den);
}

// ---------------------------------------------------------------------------
// Row 0 of every batch: reference gives uniform softmax over ALL keys
// (mask makes all scores equal) -> out[b,0,:] = mean_j V[b,j,:].
// Unique writer per (b,d) and stream-ordered after combine -> plain store.
// ---------------------------------------------------------------------------
__global__ __launch_bounds__(256) void meanv_kernel(
    const unsigned short* __restrict__ Vth, const unsigned short* __restrict__ Vtl,
    float* __restrict__ out)
{
  int bx = blockIdx.x;
  int b  = bx >> 4;
  int dg = (bx & 15) * 4;
  int t  = threadIdx.x;
  int dl = t >> 6;
  int jl = t & 63;
  int d  = dg + dl;

  const unsigned short* ph = Vth + ((size_t)(b * Dn + d)) * Sn;
  const unsigned short* pl = Vtl + ((size_t)(b * Dn + d)) * Sn;
  float s = 0.f;
#pragma unroll
  for (int it = 0; it < 4; ++it) {
    int base = it * 1024 + jl * 16;
    ushort8_t v0 = *(const ushort8_t*)(ph + base);
    ushort8_t v1 = *(const ushort8_t*)(ph + base + 8);
    ushort8_t w0 = *(const ushort8_t*)(pl + base);
    ushort8_t w1 = *(const ushort8_t*)(pl + base + 8);
#pragma unroll
    for (int e = 0; e < 8; ++e) {
      s += __uint_as_float((unsigned)v0[e] << 16);
      s += __uint_as_float((unsigned)v1[e] << 16);
      s += __uint_as_float((unsigned)w0[e] << 16);
      s += __uint_as_float((unsigned)w1[e] << 16);
    }
  }
#pragma unroll
  for (int o = 32; o > 0; o >>= 1) s += __shfl_xor(s, o, 64);
  if (jl == 0) out[(size_t)b * Sn * Dn + d] = s * (1.0f / 4096.0f);
}

// ---------------------------------------------------------------------------
extern "C" void kernel_launch(void* const* d_in, const int* in_sizes, int n_in,
                              void* d_out, int out_size, void* d_ws, size_t ws_size,
                              hipStream_t stream) {
  (void)in_sizes; (void)n_in; (void)out_size; (void)ws_size;
  const float* query = (const float*)d_in[0];
  const float* key_  = (const float*)d_in[1];
  const float* value = (const float*)d_in[2];
  const float* Wq = (const float*)d_in[3];
  const float* Wk = (const float*)d_in[4];
  const float* Wv = (const float*)d_in[5];
  float* out = (float*)d_out;

  char* w = (char*)d_ws;
  const size_t mat = (size_t)Bn * Sn * Dn * 2;  // 2 MB per bf16 matrix
  unsigned short* Qh  = (unsigned short*)(w + 0 * mat);
  unsigned short* Ql  = (unsigned short*)(w + 1 * mat);
  unsigned short* Kh  = (unsigned short*)(w + 2 * mat);
  unsigned short* Kl  = (unsigned short*)(w + 3 * mat);
  unsigned short* Vh  = (unsigned short*)(w + 4 * mat);
  unsigned short* Vl  = (unsigned short*)(w + 5 * mat);
  unsigned short* Vth = (unsigned short*)(w + 6 * mat);
  unsigned short* Vtl = (unsigned short*)(w + 7 * mat);
  float* part = (float*)(w + 8 * mat);          // 2*B*S*68 f32 = 8.5 MB

  hipLaunchKernelGGL(proj_kernel, dim3(768), dim3(256), 0, stream,
                     query, key_, value, Wq, Wk, Wv, Qh, Ql, Kh, Kl, Vh, Vl);
  hipLaunchKernelGGL(transpose_kernel, dim3(256), dim3(256), 0, stream,
                     Vh, Vl, Vth, Vtl);
  hipLaunchKernelGGL(attn_kernel, dim3(512), dim3(128), 0, stream,
                     Qh, Ql, Kh, Kl, Vth, Vtl, part);
  hipLaunchKernelGGL(combine_kernel, dim3((Bn * Sn * Dn) / 256), dim3(256), 0, stream,
                     part, out);
  hipLaunchKernelGGL(meanv_kernel, dim3(64), dim3(256), 0, stream,
                     Vth, Vtl, out);
}

// Round 6
// 207.781 us; speedup vs baseline: 1.2221x; 1.2221x over previous
//
#include <hip/hip_runtime.h>
#include <stdint.h>

#define Bn  4
#define Sn  4096
#define DIN 512
#define Dn  64
#define RS  0.18033688011112042f   /* (1/8) * log2(e) */
#define MASKV (-3.0e38f)

typedef __bf16 bf16;
typedef __bf16 bf16x8 __attribute__((ext_vector_type(8)));
typedef float  f32x16 __attribute__((ext_vector_type(16)));
typedef unsigned short ushort8_t __attribute__((ext_vector_type(8)));

__device__ __forceinline__ f32x16 mfma32(bf16x8 a, bf16x8 b, f32x16 c) {
  return __builtin_amdgcn_mfma_f32_32x32x16_bf16(a, b, c, 0, 0, 0);
}

__device__ __forceinline__ f32x16 fzero16() {
  f32x16 v;
#pragma unroll
  for (int i = 0; i < 16; ++i) v[i] = 0.f;
  return v;
}

// 16B fragment read (8 bf16) from a row-major [*][64] bf16 LDS tile with
// byte ^= ((row&7)<<4) XOR swizzle (T2).
__device__ __forceinline__ bf16x8 frag_ld(const unsigned short* base, int row, int k) {
  int off = (row << 7) + (k << 1);
  off ^= (row & 7) << 4;
  return *(const bf16x8*)((const char*)base + off);
}

// async global->LDS, 16B per lane; LDS dest must be wave-uniform base.
__device__ __forceinline__ void async16(void* lds, const void* g) {
  __builtin_amdgcn_global_load_lds(
      (const __attribute__((address_space(1))) unsigned int*)g,
      (__attribute__((address_space(3))) unsigned int*)lds, 16, 0, 0);
}

__device__ __forceinline__ unsigned int pk2(float a, float b) {
  unsigned short ra = __builtin_bit_cast(unsigned short, (bf16)a);
  unsigned short rb = __builtin_bit_cast(unsigned short, (bf16)b);
  return (unsigned int)ra | ((unsigned int)rb << 16);
}

// ---------------------------------------------------------------------------
// Projection: Y[16384x64] = X[16384x512] @ W[64x512]^T, fp32 in, hi/lo bf16 out.
// mat 0/1 (Q,K): row-major [B*S][64].  mat 2 (V): written TRANSPOSED [B][64][S]
// (saves a separate transpose kernel + 4MB of workspace).
// ---------------------------------------------------------------------------
__global__ __launch_bounds__(256) void proj_kernel(
    const float* __restrict__ Xq, const float* __restrict__ Xk, const float* __restrict__ Xv,
    const float* __restrict__ Wq, const float* __restrict__ Wk, const float* __restrict__ Wv,
    unsigned short* __restrict__ Qh, unsigned short* __restrict__ Ql,
    unsigned short* __restrict__ Kh, unsigned short* __restrict__ Kl,
    unsigned short* __restrict__ Vth, unsigned short* __restrict__ Vtl)
{
  int mat = blockIdx.x >> 8;
  int rt  = blockIdx.x & 255;
  const float* X = (mat == 0) ? Xq : (mat == 1) ? Xk : Xv;
  const float* W = (mat == 0) ? Wq : (mat == 1) ? Wk : Wv;
  unsigned short* Yh = (mat == 0) ? Qh : (mat == 1) ? Kh : Vth;
  unsigned short* Yl = (mat == 0) ? Ql : (mat == 1) ? Kl : Vtl;

  __shared__ unsigned short Xh_s[64 * 64];
  __shared__ unsigned short Xl_s[64 * 64];
  __shared__ unsigned short Wh_s[64 * 64];
  __shared__ unsigned short Wl_s[64 * 64];

  int tid  = threadIdx.x;
  int lane = tid & 63;
  int wv   = tid >> 6;
  int h    = lane >> 5;
  int c    = lane & 31;
  int srow = tid >> 2;   // staging row 0..63
  int sq   = tid & 3;

  int row0 = rt * 64;

  f32x16 acc = fzero16();

  for (int k0 = 0; k0 < DIN; k0 += 64) {
#pragma unroll
    for (int j = 0; j < 4; ++j) {
      int kk = j * 16 + sq * 4;
      int off = ((srow << 7) + (kk << 1)) ^ ((srow & 7) << 4);

      float4 xv = *(const float4*)(X + (size_t)(row0 + srow) * DIN + k0 + kk);
      bf16 bx0 = (bf16)xv.x, bx1 = (bf16)xv.y, bx2 = (bf16)xv.z, bx3 = (bf16)xv.w;
      uint2 hw, lw;
      hw.x = (unsigned)__builtin_bit_cast(unsigned short, bx0) |
             ((unsigned)__builtin_bit_cast(unsigned short, bx1) << 16);
      hw.y = (unsigned)__builtin_bit_cast(unsigned short, bx2) |
             ((unsigned)__builtin_bit_cast(unsigned short, bx3) << 16);
      lw.x = pk2(xv.x - (float)bx0, xv.y - (float)bx1);
      lw.y = pk2(xv.z - (float)bx2, xv.w - (float)bx3);
      *(uint2*)((char*)Xh_s + off) = hw;
      *(uint2*)((char*)Xl_s + off) = lw;

      float4 wv4 = *(const float4*)(W + (size_t)srow * DIN + k0 + kk);
      bf16 bw0 = (bf16)wv4.x, bw1 = (bf16)wv4.y, bw2 = (bf16)wv4.z, bw3 = (bf16)wv4.w;
      uint2 hw2, lw2;
      hw2.x = (unsigned)__builtin_bit_cast(unsigned short, bw0) |
              ((unsigned)__builtin_bit_cast(unsigned short, bw1) << 16);
      hw2.y = (unsigned)__builtin_bit_cast(unsigned short, bw2) |
              ((unsigned)__builtin_bit_cast(unsigned short, bw3) << 16);
      lw2.x = pk2(wv4.x - (float)bw0, wv4.y - (float)bw1);
      lw2.y = pk2(wv4.z - (float)bw2, wv4.w - (float)bw3);
      *(uint2*)((char*)Wh_s + off) = hw2;
      *(uint2*)((char*)Wl_s + off) = lw2;
    }
    __syncthreads();

    int ar   = (wv >> 1) * 32 + c;
    int bcol = (wv & 1) * 32 + c;
#pragma unroll
    for (int kk = 0; kk < 4; ++kk) {
      int kp = kk * 16 + h * 8;
      bf16x8 ah = frag_ld(Xh_s, ar, kp);
      bf16x8 al = frag_ld(Xl_s, ar, kp);
      bf16x8 bh = frag_ld(Wh_s, bcol, kp);
      bf16x8 bl = frag_ld(Wl_s, bcol, kp);
      acc = mfma32(ah, bh, acc);
      acc = mfma32(ah, bl, acc);
      acc = mfma32(al, bh, acc);
    }
    __syncthreads();
  }

  // C/D: row = (r&3) + 8*(r>>2) + 4*(lane>>5), col = lane&31  [guide m74/m101]
  int wr = (wv >> 1) * 32;
  int wc = (wv & 1) * 32;
  if (mat == 2) {
    // V transposed: Vt[b][d][s], d = wc+c, s = global row
#pragma unroll
    for (int r = 0; r < 16; ++r) {
      int rowl = (r & 3) + ((r >> 2) << 3) + h * 4;
      int g  = row0 + wr + rowl;          // global s-row in [0, B*S)
      int b2 = g >> 12;
      int s2 = g & (Sn - 1);
      size_t o = ((size_t)(b2 * Dn + wc + c)) * Sn + s2;
      float v = acc[r];
      bf16 hv = (bf16)v;
      Yh[o] = __builtin_bit_cast(unsigned short, hv);
      Yl[o] = __builtin_bit_cast(unsigned short, (bf16)(v - (float)hv));
    }
  } else {
#pragma unroll
    for (int r = 0; r < 16; ++r) {
      int rowl = (r & 3) + ((r >> 2) << 3) + h * 4;
      size_t o = (size_t)(row0 + wr + rowl) * Dn + wc + c;
      float v = acc[r];
      bf16 hv = (bf16)v;
      Yh[o] = __builtin_bit_cast(unsigned short, hv);
      Yl[o] = __builtin_bit_cast(unsigned short, (bf16)(v - (float)hv));
    }
  }
}

// ---------------------------------------------------------------------------
// Flash attention v3: 256 threads (4 waves x 32 q-rows = 128 q-rows/block),
// split-K=4 (stride-4 key tiles), double-buffered 64KB LDS shared by 4 waves.
// Grid = 32 qtb x 4 sk x 4 b = 512 blocks -> 2 blocks/CU -> 2 waves/SIMD.
// ---------------------------------------------------------------------------
__global__ __launch_bounds__(256) void attn_kernel(
    const unsigned short* __restrict__ Qh, const unsigned short* __restrict__ Ql,
    const unsigned short* __restrict__ Kh, const unsigned short* __restrict__ Kl,
    const unsigned short* __restrict__ Vth, const unsigned short* __restrict__ Vtl,
    float* __restrict__ part)
{
  int bx   = blockIdx.x;
  int qtb  = 31 - (bx >> 4);     // largest q-blocks dispatched first
  int sk   = (bx >> 2) & 3;
  int b    = bx & 3;
  int tid  = threadIdx.x;
  int wv   = tid >> 6;
  int lane = tid & 63;
  int h    = lane >> 5;
  int c    = lane & 31;
  int q_base = qtb * 128 + wv * 32;

  __shared__ unsigned short Kh_s[2][64 * 64];
  __shared__ unsigned short Kl_s[2][64 * 64];
  __shared__ unsigned short Vh_s[2][64 * 64];
  __shared__ unsigned short Vl_s[2][64 * 64];

  // Q B-fragments (B[k=d][n=q] = Q[q][d])
  bf16x8 qhi[4], qlo[4];
  {
    const unsigned short* qp  = Qh + ((size_t)(b * Sn) + q_base + c) * Dn;
    const unsigned short* qp2 = Ql + ((size_t)(b * Sn) + q_base + c) * Dn;
#pragma unroll
    for (int kk = 0; kk < 4; ++kk) {
      qhi[kk] = *(const bf16x8*)(qp + kk * 16 + h * 8);
      qlo[kk] = *(const bf16x8*)(qp2 + kk * 16 + h * 8);
    }
  }

  f32x16 o0 = fzero16(), o1 = fzero16();
  float m = MASKV, lsum = 0.f;

  int nt   = 2 * qtb + 2;            // key tiles spanned by this q-block
  int ti_d = 2 * qtb + (wv >> 1);    // this wave's diagonal tile
  int qrel = (wv & 1) * 32 + c;      // q offset within diagonal tile

  int l8   = lane >> 3;
  int slot = (lane & 7) ^ (l8 & 7);  // pre-swizzled global 16B-slot (rule #21)

  // 4 waves cooperatively stage 32KB: wave wv stages row-chunks {2wv, 2wv+1}.
  auto stage = [&](int sb, int ti) {
    size_t j0 = (size_t)ti * 64;
#pragma unroll
    for (int i = 0; i < 2; ++i) {
      int rowbase = (wv * 2 + i) * 8;
      int row = rowbase + l8;
      const char* gk  = (const char*)Kh + ((size_t)(b * Sn) + j0 + row) * 128 + slot * 16;
      const char* gk2 = (const char*)Kl + ((size_t)(b * Sn) + j0 + row) * 128 + slot * 16;
      async16(&Kh_s[sb][rowbase * 64], gk);
      async16(&Kl_s[sb][rowbase * 64], gk2);
      const char* gv  = (const char*)Vth + ((size_t)(b * Dn) + row) * (Sn * 2) + j0 * 2 + slot * 16;
      const char* gv2 = (const char*)Vtl + ((size_t)(b * Dn) + row) * (Sn * 2) + j0 * 2 + slot * 16;
      async16(&Vh_s[sb][rowbase * 64], gv);
      async16(&Vl_s[sb][rowbase * 64], gv2);
    }
  };

  int buf = 0;
  stage(0, sk);
  __syncthreads();

  for (int ti = sk; ti < nt; ti += 4) {
    if (ti + 4 < nt) stage(buf ^ 1, ti + 4);

    bool active = (ti <= ti_d);      // wave-uniform: skip fully-masked tiles
    if (active) {
      const unsigned short* KhT = Kh_s[buf];
      const unsigned short* KlT = Kl_s[buf];
      const unsigned short* VhT = Vh_s[buf];
      const unsigned short* VlT = Vl_s[buf];

      // --- QK^T (swapped: S^T[key][q]), 4 independent MFMA chains ---
      f32x16 s0a = fzero16(), s0b = fzero16(), s1a = fzero16(), s1b = fzero16();
#pragma unroll
      for (int kk = 0; kk < 4; ++kk) {
        int kp = kk * 16 + h * 8;
        bf16x8 k0h = frag_ld(KhT, c, kp);
        bf16x8 k0l = frag_ld(KlT, c, kp);
        bf16x8 k1h = frag_ld(KhT, 32 + c, kp);
        bf16x8 k1l = frag_ld(KlT, 32 + c, kp);
        if (kk < 2) {
          s0a = mfma32(k0h, qhi[kk], s0a); s0a = mfma32(k0h, qlo[kk], s0a); s0a = mfma32(k0l, qhi[kk], s0a);
          s1a = mfma32(k1h, qhi[kk], s1a); s1a = mfma32(k1h, qlo[kk], s1a); s1a = mfma32(k1l, qhi[kk], s1a);
        } else {
          s0b = mfma32(k0h, qhi[kk], s0b); s0b = mfma32(k0h, qlo[kk], s0b); s0b = mfma32(k0l, qhi[kk], s0b);
          s1b = mfma32(k1h, qhi[kk], s1b); s1b = mfma32(k1h, qlo[kk], s1b); s1b = mfma32(k1l, qhi[kk], s1b);
        }
      }
      f32x16 s0 = s0a + s0b;
      f32x16 s1 = s1a + s1b;

      // --- causal mask (diagonal tile only): key >= q -> MASKV ---
      if (ti == ti_d) {
#pragma unroll
        for (int r = 0; r < 16; ++r) {
          int koff = (r & 3) + ((r >> 2) << 3) + h * 4;
          if (koff >= qrel)      s0[r] = MASKV;
          if (32 + koff >= qrel) s1[r] = MASKV;
        }
      }

      // --- online softmax (lane holds 32 keys of q-row c; partner = lane^32) ---
      float mt = s0[0];
#pragma unroll
      for (int r = 1; r < 16; ++r) mt = fmaxf(mt, s0[r]);
#pragma unroll
      for (int r = 0; r < 16; ++r) mt = fmaxf(mt, s1[r]);
      mt = fmaxf(mt, __shfl_xor(mt, 32, 64));
      float mnew = fmaxf(m, mt);
      float al = exp2f((m - mnew) * RS);

      float p0[16], p1[16];
      float rsum = 0.f;
#pragma unroll
      for (int r = 0; r < 16; ++r) {
        p0[r] = exp2f((s0[r] - mnew) * RS);
        p1[r] = exp2f((s1[r] - mnew) * RS);
        rsum += p0[r] + p1[r];
      }
      rsum += __shfl_xor(rsum, 32, 64);
      lsum = lsum * al + rsum;
      m = mnew;

      // --- rescale O ---
#pragma unroll
      for (int r = 0; r < 16; ++r) {
        int koff = (r & 3) + ((r >> 2) << 3) + h * 4;
        float ar = __shfl(al, (lane & 32) | koff, 64);
        o0[r] *= ar;
        o1[r] *= ar;
      }

      // --- PV: out[q][d] += P[q][keys] * V[keys][d] ---
#pragma unroll
      for (int ks = 0; ks < 2; ++ks) {
#pragma unroll
        for (int kk2 = 0; kk2 < 2; ++kk2) {
          float e0[4], e1[4];
#pragma unroll
          for (int x = 0; x < 4; ++x) {
            float vh0 = ks ? p1[(2 * kk2 + 0) * 4 + x] : p0[(2 * kk2 + 0) * 4 + x];
            float vh1 = ks ? p1[(2 * kk2 + 1) * 4 + x] : p0[(2 * kk2 + 1) * 4 + x];
            float own  = h ? vh1 : vh0;
            float send = h ? vh0 : vh1;
            float recv = __shfl_xor(send, 32, 64);
            e0[x] = h ? recv : own;
            e1[x] = h ? own : recv;
          }
          bf16x8 pah, pal;
#pragma unroll
          for (int x = 0; x < 4; ++x) {
            bf16 hh = (bf16)e0[x];
            pah[x] = hh;
            pal[x] = (bf16)(e0[x] - (float)hh);
            bf16 h2 = (bf16)e1[x];
            pah[4 + x] = h2;
            pal[4 + x] = (bf16)(e1[x] - (float)h2);
          }
          int kp = ks * 32 + kk2 * 16 + h * 8;
          bf16x8 v0h = frag_ld(VhT, c, kp);
          bf16x8 v0l = frag_ld(VlT, c, kp);
          bf16x8 v1h = frag_ld(VhT, 32 + c, kp);
          bf16x8 v1l = frag_ld(VlT, 32 + c, kp);
          o0 = mfma32(pah, v0h, o0);
          o0 = mfma32(pah, v0l, o0);
          o0 = mfma32(pal, v0h, o0);
          o1 = mfma32(pah, v1h, o1);
          o1 = mfma32(pah, v1l, o1);
          o1 = mfma32(pal, v1h, o1);
        }
      }
    }

    __syncthreads();
    buf ^= 1;
  }

  // --- write partials: [sk][b][s]: O[64], m, l (stride 68 f32) ---
  float* pb = part + ((size_t)(sk * Bn + b) * Sn + q_base) * 68;
#pragma unroll
  for (int r = 0; r < 16; ++r) {
    int koff = (r & 3) + ((r >> 2) << 3) + h * 4;
    float* pr = pb + (size_t)koff * 68;
    pr[c]      = o0[r];
    pr[32 + c] = o1[r];
  }
  if (h == 0) {
    float* pr = pb + (size_t)c * 68;
    pr[64] = m;
    pr[65] = lsum;
  }
}

// ---------------------------------------------------------------------------
// Combine the 4 split-K partials; zero row 0 (mean-V kernel fills it).
// ---------------------------------------------------------------------------
__global__ __launch_bounds__(256) void combine_kernel(
    const float* __restrict__ part, float* __restrict__ out)
{
  size_t idx = (size_t)blockIdx.x * 256 + threadIdx.x;
  int d = (int)(idx & 63);
  int s = (int)((idx >> 6) & (Sn - 1));
  int b = (int)(idx >> 18);
  const float* p[4];
  float ms = MASKV;
#pragma unroll
  for (int i = 0; i < 4; ++i) {
    p[i] = part + ((size_t)(i * Bn + b) * Sn + s) * 68;
    ms = fmaxf(ms, p[i][64]);
  }
  float num = 0.f, den = 0.f;
#pragma unroll
  for (int i = 0; i < 4; ++i) {
    float a = exp2f((p[i][64] - ms) * RS);
    num += a * p[i][d];
    den += a * p[i][65];
  }
  out[idx] = (s == 0) ? 0.0f : (num / den);
}

// ---------------------------------------------------------------------------
// Row 0: out[b,0,:] = mean_j V[b,j,:].
// ---------------------------------------------------------------------------
__global__ __launch_bounds__(256) void meanv_kernel(
    const unsigned short* __restrict__ Vth, const unsigned short* __restrict__ Vtl,
    float* __restrict__ out)
{
  int bx = blockIdx.x;
  int b  = bx >> 4;
  int dg = (bx & 15) * 4;
  int t  = threadIdx.x;
  int dl = t >> 6;
  int jl = t & 63;
  int d  = dg + dl;

  const unsigned short* ph = Vth + ((size_t)(b * Dn + d)) * Sn;
  const unsigned short* pl = Vtl + ((size_t)(b * Dn + d)) * Sn;
  float s = 0.f;
#pragma unroll
  for (int it = 0; it < 4; ++it) {
    int base = it * 1024 + jl * 16;
    ushort8_t v0 = *(const ushort8_t*)(ph + base);
    ushort8_t v1 = *(const ushort8_t*)(ph + base + 8);
    ushort8_t w0 = *(const ushort8_t*)(pl + base);
    ushort8_t w1 = *(const ushort8_t*)(pl + base + 8);
#pragma unroll
    for (int e = 0; e < 8; ++e) {
      s += __uint_as_float((unsigned)v0[e] << 16);
      s += __uint_as_float((unsigned)v1[e] << 16);
      s += __uint_as_float((unsigned)w0[e] << 16);
      s += __uint_as_float((unsigned)w1[e] << 16);
    }
  }
#pragma unroll
  for (int o = 32; o > 0; o >>= 1) s += __shfl_xor(s, o, 64);
  if (jl == 0) out[(size_t)b * Sn * Dn + d] = s * (1.0f / 4096.0f);
}

// ---------------------------------------------------------------------------
extern "C" void kernel_launch(void* const* d_in, const int* in_sizes, int n_in,
                              void* d_out, int out_size, void* d_ws, size_t ws_size,
                              hipStream_t stream) {
  (void)in_sizes; (void)n_in; (void)out_size; (void)ws_size;
  const float* query = (const float*)d_in[0];
  const float* key_  = (const float*)d_in[1];
  const float* value = (const float*)d_in[2];
  const float* Wq = (const float*)d_in[3];
  const float* Wk = (const float*)d_in[4];
  const float* Wv = (const float*)d_in[5];
  float* out = (float*)d_out;

  char* w = (char*)d_ws;
  const size_t mat = (size_t)Bn * Sn * Dn * 2;  // 2 MB per bf16 matrix
  unsigned short* Qh  = (unsigned short*)(w + 0 * mat);
  unsigned short* Ql  = (unsigned short*)(w + 1 * mat);
  unsigned short* Kh  = (unsigned short*)(w + 2 * mat);
  unsigned short* Kl  = (unsigned short*)(w + 3 * mat);
  unsigned short* Vth = (unsigned short*)(w + 4 * mat);
  unsigned short* Vtl = (unsigned short*)(w + 5 * mat);
  float* part = (float*)(w + 6 * mat);          // 4*B*S*68 f32 = 17.8 MB -> total 29.8 MB

  hipLaunchKernelGGL(proj_kernel, dim3(768), dim3(256), 0, stream,
                     query, key_, value, Wq, Wk, Wv, Qh, Ql, Kh, Kl, Vth, Vtl);
  hipLaunchKernelGGL(attn_kernel, dim3(512), dim3(256), 0, stream,
                     Qh, Ql, Kh, Kl, Vth, Vtl, part);
  hipLaunchKernelGGL(combine_kernel, dim3((Bn * Sn * Dn) / 256), dim3(256), 0, stream,
                     part, out);
  hipLaunchKernelGGL(meanv_kernel, dim3(64), dim3(256), 0, stream,
                     Vth, Vtl, out);
}